// Round 1
// baseline (974.527 us; speedup 1.0000x reference)
//
#include <hip/hip_runtime.h>
#include <math.h>

#define NN 1000000
#define HH 32
#define FIN 16

// ws layout (floats):
//   WxT  [4][32][16]  at 0      (2048)  : WxT[g][j][k] = Wx[k*128 + g*32 + j]
//   WhT  [4][32][32]  at 2048   (4096)  : WhT[g][j][k] = Wh[k*128 + g*32 + j]
//   bcomb[4][32]      at 6144   (128)   : bx + bh + b_{i,f,c,o}
// total 6272 floats = 25088 bytes

__global__ void prep_kernel(const float* __restrict__ Wx, const float* __restrict__ bx,
                            const float* __restrict__ Wh, const float* __restrict__ bh,
                            const float* __restrict__ b_i, const float* __restrict__ b_f,
                            const float* __restrict__ b_c, const float* __restrict__ b_o,
                            float* __restrict__ ws) {
    int idx = blockIdx.x * blockDim.x + threadIdx.x;
    if (idx < 2048) {
        int g = idx >> 9;          // / (32*16)
        int r = idx & 511;
        int j = r >> 4;
        int k = r & 15;
        ws[idx] = Wx[k * 128 + g * 32 + j];
    } else if (idx < 2048 + 4096) {
        int t = idx - 2048;
        int g = t >> 10;           // / (32*32)
        int r = t & 1023;
        int j = r >> 5;
        int k = r & 31;
        ws[idx] = Wh[k * 128 + g * 32 + j];
    } else if (idx < 6272) {
        int t = idx - 6144;
        int g = t >> 5;
        int j = t & 31;
        const float* bg = (g == 0) ? b_i : (g == 1) ? b_f : (g == 2) ? b_c : b_o;
        ws[idx] = bx[g * 32 + j] + bh[g * 32 + j] + bg[j];
    }
}

__device__ __forceinline__ float sigf(float x) {
    return 1.0f / (1.0f + __expf(-x));
}
__device__ __forceinline__ float tanh_fast(float x) {
    // tanh(x) = 2*sigmoid(2x) - 1; exp overflow/underflow saturates correctly.
    return 2.0f / (1.0f + __expf(-2.0f * x)) - 1.0f;
}

__global__ __launch_bounds__(256) void gclstm_kernel(
    const float* __restrict__ x, const float* __restrict__ h, const float* __restrict__ c,
    const float* __restrict__ w_ci, const float* __restrict__ w_cf, const float* __restrict__ w_co,
    const float* __restrict__ Wl, const float* __restrict__ bl,
    const float* __restrict__ ws,
    float* __restrict__ out, float* __restrict__ Hout, float* __restrict__ Cout)
{
    int n = blockIdx.x * 256 + threadIdx.x;
    if (n >= NN) return;

    // Per-node inputs into registers (vectorized 16B loads).
    float xr[16];
    {
        const float4* xp = reinterpret_cast<const float4*>(x + (size_t)n * FIN);
        #pragma unroll
        for (int i = 0; i < 4; ++i) {
            float4 v = xp[i];
            xr[i * 4 + 0] = v.x; xr[i * 4 + 1] = v.y; xr[i * 4 + 2] = v.z; xr[i * 4 + 3] = v.w;
        }
    }
    float hr[32];
    {
        const float4* hp = reinterpret_cast<const float4*>(h + (size_t)n * HH);
        #pragma unroll
        for (int i = 0; i < 8; ++i) {
            float4 v = hp[i];
            hr[i * 4 + 0] = v.x; hr[i * 4 + 1] = v.y; hr[i * 4 + 2] = v.z; hr[i * 4 + 3] = v.w;
        }
    }
    const float4* cp = reinterpret_cast<const float4*>(c + (size_t)n * HH);

    const float* WxT   = ws;          // [4][32][16]
    const float* WhT   = ws + 2048;   // [4][32][32]
    const float* bcomb = ws + 6144;   // [4][32]

    float4* Hp = reinterpret_cast<float4*>(Hout + (size_t)n * HH);
    float4* Cp = reinterpret_cast<float4*>(Cout + (size_t)n * HH);

    float out_acc = 0.0f;

    for (int jq = 0; jq < 8; ++jq) {   // channel quads
        float4 cq = cp[jq];
        float cv[4] = {cq.x, cq.y, cq.z, cq.w};

        float acc[4][4];
        #pragma unroll
        for (int g = 0; g < 4; ++g)
            #pragma unroll
            for (int jj = 0; jj < 4; ++jj)
                acc[g][jj] = bcomb[g * 32 + jq * 4 + jj];

        // Dense gate GEMV: weights are wave-uniform -> scalar (SGPR) loads.
        #pragma unroll
        for (int g = 0; g < 4; ++g) {
            #pragma unroll
            for (int jj = 0; jj < 4; ++jj) {
                int j = jq * 4 + jj;
                const float* wx = WxT + (g * 32 + j) * 16;
                const float* wh = WhT + (g * 32 + j) * 32;
                float a = acc[g][jj];
                #pragma unroll
                for (int k = 0; k < 16; ++k) a = fmaf(xr[k], wx[k], a);
                #pragma unroll
                for (int k = 0; k < 32; ++k) a = fmaf(hr[k], wh[k], a);
                acc[g][jj] = a;
            }
        }

        float co[4], ho[4];
        #pragma unroll
        for (int jj = 0; jj < 4; ++jj) {
            int j = jq * 4 + jj;
            float I  = sigf(fmaf(w_ci[j], cv[jj], acc[0][jj]));
            float Fg = sigf(fmaf(w_cf[j], cv[jj], acc[1][jj]));
            float T  = tanh_fast(acc[2][jj]);
            float Cn = Fg * cv[jj] + I * T;
            float O  = sigf(fmaf(w_co[j], Cn, acc[3][jj]));
            float Hn = O * tanh_fast(Cn);
            co[jj] = Cn; ho[jj] = Hn;
            out_acc = fmaf(fmaxf(Hn, 0.0f), Wl[j], out_acc);
        }
        Cp[jq] = make_float4(co[0], co[1], co[2], co[3]);
        Hp[jq] = make_float4(ho[0], ho[1], ho[2], ho[3]);
    }

    out[n] = out_acc + bl[0];
}

extern "C" void kernel_launch(void* const* d_in, const int* in_sizes, int n_in,
                              void* d_out, int out_size, void* d_ws, size_t ws_size,
                              hipStream_t stream) {
    const float* x    = (const float*)d_in[0];
    // d_in[1] edge_index, d_in[2] edge_weight: inert (ChebConv K=1 never propagates).
    const float* h    = (const float*)d_in[3];
    const float* c    = (const float*)d_in[4];
    const float* Wx   = (const float*)d_in[5];
    const float* bx   = (const float*)d_in[6];
    const float* Wh   = (const float*)d_in[7];
    const float* bh   = (const float*)d_in[8];
    const float* w_ci = (const float*)d_in[9];
    const float* w_cf = (const float*)d_in[10];
    const float* w_co = (const float*)d_in[11];
    const float* b_i  = (const float*)d_in[12];
    const float* b_f  = (const float*)d_in[13];
    const float* b_c  = (const float*)d_in[14];
    const float* b_o  = (const float*)d_in[15];
    const float* Wl   = (const float*)d_in[16];
    const float* bl   = (const float*)d_in[17];

    float* ws   = (float*)d_ws;
    float* out  = (float*)d_out;               // N floats
    float* Hout = out + (size_t)NN;            // N*32 floats
    float* Cout = Hout + (size_t)NN * HH;      // N*32 floats

    hipLaunchKernelGGL(prep_kernel, dim3(25), dim3(256), 0, stream,
                       Wx, bx, Wh, bh, b_i, b_f, b_c, b_o, ws);

    hipLaunchKernelGGL(gclstm_kernel, dim3((NN + 255) / 256), dim3(256), 0, stream,
                       x, h, c, w_ci, w_cf, w_co, Wl, bl, ws,
                       out, Hout, Cout);
}

// Round 4
// 756.092 us; speedup vs baseline: 1.2889x; 1.2889x over previous
//
#include <hip/hip_runtime.h>
#include <math.h>

#define NN 1000000
#define HH 32
#define FIN 16

// ws layout (floats):
//   wcat [32][4][48] at 0    (6144) : wcat[j][g][k] = k<16 ? Wx[k*128+g*32+j] : Wh[(k-16)*128+g*32+j]
//   bcomb[4][32]     at 6144 (128)  : bx + bh + b_{i,f,c,o}
__global__ void prep_kernel(const float* __restrict__ Wx, const float* __restrict__ bx,
                            const float* __restrict__ Wh, const float* __restrict__ bh,
                            const float* __restrict__ b_i, const float* __restrict__ b_f,
                            const float* __restrict__ b_c, const float* __restrict__ b_o,
                            float* __restrict__ ws) {
    int idx = blockIdx.x * blockDim.x + threadIdx.x;
    if (idx < 6144) {
        int j = idx / 192;
        int r = idx - j * 192;
        int g = r / 48;
        int k = r - g * 48;
        ws[idx] = (k < 16) ? Wx[k * 128 + g * 32 + j] : Wh[(k - 16) * 128 + g * 32 + j];
    } else if (idx < 6272) {
        int t = idx - 6144;
        int g = t >> 5, j = t & 31;
        const float* bg = (g == 0) ? b_i : (g == 1) ? b_f : (g == 2) ? b_c : b_o;
        ws[idx] = bx[g * 32 + j] + bh[g * 32 + j] + bg[j];
    }
}

__device__ __forceinline__ float sigf(float x) {
    return 1.0f / (1.0f + __expf(-x));
}
__device__ __forceinline__ float tanh_fast(float x) {
    return 2.0f / (1.0f + __expf(-2.0f * x)) - 1.0f;
}

__global__ __launch_bounds__(256, 4) void gclstm_kernel(
    const float* __restrict__ x, const float* __restrict__ h, const float* __restrict__ c,
    const float* __restrict__ w_ci, const float* __restrict__ w_cf, const float* __restrict__ w_co,
    const float* __restrict__ Wl, const float* __restrict__ bl,
    const float* __restrict__ ws,
    float* __restrict__ out, float* __restrict__ Hout, float* __restrict__ Cout)
{
    __shared__ float4 buf[2048];   // 32KB: output transpose staging

    const int t    = threadIdx.x;
    const int base = blockIdx.x * 256;
    const int n    = base + t;
    const int nc   = (n < NN) ? n : (NN - 1);   // clamp: no early return (barriers below)

    // Per-node inputs into registers (16B loads).
    float xr[16];
    {
        const float4* xp = reinterpret_cast<const float4*>(x + (size_t)nc * FIN);
        #pragma unroll
        for (int i = 0; i < 4; ++i) {
            float4 v = xp[i];
            xr[i*4+0] = v.x; xr[i*4+1] = v.y; xr[i*4+2] = v.z; xr[i*4+3] = v.w;
        }
    }
    float hr[32];
    {
        const float4* hp = reinterpret_cast<const float4*>(h + (size_t)nc * HH);
        #pragma unroll
        for (int i = 0; i < 8; ++i) {
            float4 v = hp[i];
            hr[i*4+0] = v.x; hr[i*4+1] = v.y; hr[i*4+2] = v.z; hr[i*4+3] = v.w;
        }
    }
    const float4* cp4 = reinterpret_cast<const float4*>(c + (size_t)nc * HH);

    const float* wcat  = ws;          // [32][4][48], wave-uniform -> s_load
    const float* bcomb = ws + 6144;   // [4][32]

    float4 co_all[8];                 // C output held in regs (static idx via full unroll)
    float  out_acc = 0.0f;

    #pragma unroll
    for (int jq = 0; jq < 8; ++jq) {
        float4 cq = cp4[jq];
        float cv[4] = {cq.x, cq.y, cq.z, cq.w};
        float ho[4], co[4];

        #pragma unroll
        for (int jj = 0; jj < 4; ++jj) {
            const int j = jq * 4 + jj;
            const float* w = wcat + j * 192;   // 4 gates x 48 contiguous
            float a0 = bcomb[j], a1 = bcomb[32 + j], a2 = bcomb[64 + j], a3 = bcomb[96 + j];
            #pragma unroll
            for (int k = 0; k < 16; ++k) {     // 4 independent chains per k -> issue-bound
                float xv = xr[k];
                a0 = fmaf(xv, w[      k], a0);
                a1 = fmaf(xv, w[ 48 + k], a1);
                a2 = fmaf(xv, w[ 96 + k], a2);
                a3 = fmaf(xv, w[144 + k], a3);
            }
            #pragma unroll
            for (int k = 0; k < 32; ++k) {
                float hv = hr[k];
                a0 = fmaf(hv, w[ 16 + k], a0);
                a1 = fmaf(hv, w[ 64 + k], a1);
                a2 = fmaf(hv, w[112 + k], a2);
                a3 = fmaf(hv, w[160 + k], a3);
            }
            float cvv = cv[jj];
            float I  = sigf(fmaf(w_ci[j], cvv, a0));
            float Fg = sigf(fmaf(w_cf[j], cvv, a1));
            float T  = tanh_fast(a2);
            float Cn = Fg * cvv + I * T;
            float O  = sigf(fmaf(w_co[j], Cn, a3));
            float Hn = O * tanh_fast(Cn);
            out_acc  = fmaf(fmaxf(Hn, 0.0f), Wl[j], out_acc);
            ho[jj] = Hn; co[jj] = Cn;
        }
        // XOR-swizzled f4 index: conflict-free write (8 bank-groups x 8 lanes)
        buf[t * 8 + (jq ^ (t & 7))] = make_float4(ho[0], ho[1], ho[2], ho[3]);
        co_all[jq] = make_float4(co[0], co[1], co[2], co[3]);
    }

    if (n < NN) out[n] = out_acc + bl[0];

    __syncthreads();
    {   // drain H: lane t writes f4 flat index t+i*256 -> fully coalesced 1KB/instr
        float4* Hf4 = reinterpret_cast<float4*>(Hout) + (size_t)base * 8;
        #pragma unroll
        for (int i = 0; i < 8; ++i) {
            int f = t + i * 256;
            int nl = f >> 3, q = f & 7;
            if (base + nl < NN)
                Hf4[f] = buf[nl * 8 + (q ^ (nl & 7))];
        }
    }
    __syncthreads();
    #pragma unroll
    for (int jq = 0; jq < 8; ++jq)
        buf[t * 8 + (jq ^ (t & 7))] = co_all[jq];
    __syncthreads();
    {   // drain C
        float4* Cf4 = reinterpret_cast<float4*>(Cout) + (size_t)base * 8;
        #pragma unroll
        for (int i = 0; i < 8; ++i) {
            int f = t + i * 256;
            int nl = f >> 3, q = f & 7;
            if (base + nl < NN)
                Cf4[f] = buf[nl * 8 + (q ^ (nl & 7))];
        }
    }
}

extern "C" void kernel_launch(void* const* d_in, const int* in_sizes, int n_in,
                              void* d_out, int out_size, void* d_ws, size_t ws_size,
                              hipStream_t stream) {
    const float* x    = (const float*)d_in[0];
    // d_in[1] edge_index, d_in[2] edge_weight: inert (ChebConv K=1 never propagates).
    const float* h    = (const float*)d_in[3];
    const float* c    = (const float*)d_in[4];
    const float* Wx   = (const float*)d_in[5];
    const float* bx   = (const float*)d_in[6];
    const float* Wh   = (const float*)d_in[7];
    const float* bh   = (const float*)d_in[8];
    const float* w_ci = (const float*)d_in[9];
    const float* w_cf = (const float*)d_in[10];
    const float* w_co = (const float*)d_in[11];
    const float* b_i  = (const float*)d_in[12];
    const float* b_f  = (const float*)d_in[13];
    const float* b_c  = (const float*)d_in[14];
    const float* b_o  = (const float*)d_in[15];
    const float* Wl   = (const float*)d_in[16];
    const float* bl   = (const float*)d_in[17];

    float* ws   = (float*)d_ws;
    float* out  = (float*)d_out;               // N floats
    float* Hout = out + (size_t)NN;            // N*32 floats
    float* Cout = Hout + (size_t)NN * HH;      // N*32 floats

    hipLaunchKernelGGL(prep_kernel, dim3(25), dim3(256), 0, stream,
                       Wx, bx, Wh, bh, b_i, b_f, b_c, b_o, ws);

    hipLaunchKernelGGL(gclstm_kernel, dim3((NN + 255) / 256), dim3(256), 0, stream,
                       x, h, c, w_ci, w_cf, w_co, Wl, bl, ws,
                       out, Hout, Cout);
}